// Round 4
// baseline (237.725 us; speedup 1.0000x reference)
//
#include <hip/hip_runtime.h>
#include <math.h>

#define N_LAYERS 101

// Clang-native vector type: __builtin_nontemporal_store requires it
// (HIP's float4 is a class and is rejected).
typedef float f32x4 __attribute__((ext_vector_type(4)));

// Prepass (1 block, 128 threads): coalesced parallel load of w/b into LDS,
// then thread 0 composes the 101 layers into F(t) = max(A*t + B, C).
// Valid when w_i >= 0 for i >= 1 (max(At+B,C) closed under h->max(w*h+b,0),
// w>=0):  max(w*max(At+B,C)+b, 0) = max(wA*t + wB+b, max(wC+b, 0)).
// Serial part is ~101 x 8 dependent cycles ~ 0.3 us; loads are 2 coalesced
// transactions (the round-0 prepass died on 202 SERIAL global loads).
__global__ void collapse_abc(const float* __restrict__ w,
                             const float* __restrict__ b,
                             float* __restrict__ abc) {
    __shared__ float ws[N_LAYERS];
    __shared__ float bs[N_LAYERS];
    const int t = threadIdx.x;
    if (t < N_LAYERS) { ws[t] = w[t]; bs[t] = b[t]; }
    __syncthreads();
    if (t == 0) {
        float A = ws[0], B = bs[0], C = 0.0f, ok = 1.0f;
        for (int i = 1; i < N_LAYERS; ++i) {
            const float wi = ws[i], bi = bs[i];
            if (wi < 0.0f) ok = 0.0f;
            A = wi * A;
            B = fmaf(wi, B, bi);
            C = fmaxf(fmaf(wi, C, bi), 0.0f);
        }
        abc[0] = A; abc[1] = B; abc[2] = C; abc[3] = ok;
    }
    // Also stage w/b copies for the (never-taken) exact fallback path.
    if (t < N_LAYERS) {
        abc[8 + t] = w[t];
        abc[8 + N_LAYERS + t] = b[t];
    }
}

// Main kernel: pure streaming. 4 independent block-chunked float4 loads per
// thread (ILP/queue depth), 2 VALU ops/elem, nontemporal stores (write-once
// output -> don't evict the input from L2/L3).
__global__ __launch_bounds__(256) void apply_affine(
    const f32x4* __restrict__ x4,
    const float* __restrict__ x,        // scalar view for tail
    const float* __restrict__ abc,
    f32x4* __restrict__ o4,
    float* __restrict__ o,
    int n4, int n) {
    __shared__ float ws[N_LAYERS];      // fallback only (808 B, free)
    __shared__ float bs[N_LAYERS];

    const float A = abc[0], B = abc[1], C = abc[2];
    const bool fast = (abc[3] != 0.0f);   // block-uniform branch

    const int gtid = blockIdx.x * blockDim.x + threadIdx.x;
    const int gsz  = gridDim.x * blockDim.x;

    if (fast) {
        // Block b owns float4 indices [b*1024, b*1024+1024); thread t takes
        // t, t+256, t+512, t+768 — coalesced, 4 loads in flight per thread.
        const int i0 = blockIdx.x * 1024 + threadIdx.x;
        const int i1 = i0 + 256, i2 = i0 + 512, i3 = i0 + 768;
        f32x4 v0, v1, v2, v3;
        if (i0 < n4) v0 = x4[i0];
        if (i1 < n4) v1 = x4[i1];
        if (i2 < n4) v2 = x4[i2];
        if (i3 < n4) v3 = x4[i3];
        #define APPLY(v) \
            v.x = fmaxf(fmaf(A, v.x, B), C); \
            v.y = fmaxf(fmaf(A, v.y, B), C); \
            v.z = fmaxf(fmaf(A, v.z, B), C); \
            v.w = fmaxf(fmaf(A, v.w, B), C);
        if (i0 < n4) { APPLY(v0); __builtin_nontemporal_store(v0, &o4[i0]); }
        if (i1 < n4) { APPLY(v1); __builtin_nontemporal_store(v1, &o4[i1]); }
        if (i2 < n4) { APPLY(v2); __builtin_nontemporal_store(v2, &o4[i2]); }
        if (i3 < n4) { APPLY(v3); __builtin_nontemporal_store(v3, &o4[i3]); }
        #undef APPLY
        // Scalar tail (n % 4 != 0) — empty for this problem (n = 2^25).
        for (int i = n4 * 4 + gtid; i < n; i += gsz) {
            o[i] = fmaxf(fmaf(A, x[i], B), C);
        }
    } else {
        // Exact fallback (never taken for these inputs): full 101-layer
        // chain from LDS. unroll 1 keeps the deep loop from inflating the
        // whole kernel's VGPR allocation.
        for (int i = threadIdx.x; i < N_LAYERS; i += blockDim.x) {
            ws[i] = abc[8 + i];
            bs[i] = abc[8 + N_LAYERS + i];
        }
        __syncthreads();
        #pragma unroll 1
        for (int i = gtid; i < n4; i += gsz) {
            f32x4 v = x4[i];
            #pragma unroll 1
            for (int l = 0; l < N_LAYERS; ++l) {
                const float wl = ws[l], bl = bs[l];
                v.x = fmaxf(fmaf(wl, v.x, bl), 0.0f);
                v.y = fmaxf(fmaf(wl, v.y, bl), 0.0f);
                v.z = fmaxf(fmaf(wl, v.z, bl), 0.0f);
                v.w = fmaxf(fmaf(wl, v.w, bl), 0.0f);
            }
            o4[i] = v;
        }
        #pragma unroll 1
        for (int i = n4 * 4 + gtid; i < n; i += gsz) {
            float v = x[i];
            #pragma unroll 1
            for (int l = 0; l < N_LAYERS; ++l) {
                v = fmaxf(fmaf(ws[l], v, bs[l]), 0.0f);
            }
            o[i] = v;
        }
    }
}

extern "C" void kernel_launch(void* const* d_in, const int* in_sizes, int n_in,
                              void* d_out, int out_size, void* d_ws, size_t ws_size,
                              hipStream_t stream) {
    const float* x = (const float*)d_in[0];
    const float* w = (const float*)d_in[1];
    const float* b = (const float*)d_in[2];
    float* out = (float*)d_out;
    float* abc = (float*)d_ws;            // [0..3]=A,B,C,ok  [8..]=w,b copies

    const int n  = in_sizes[0];
    const int n4 = n / 4;

    collapse_abc<<<1, 128, 0, stream>>>(w, b, abc);

    const int blocks = (n4 + 1023) / 1024;   // 4 float4 per thread
    apply_affine<<<blocks, 256, 0, stream>>>(
        (const f32x4*)x, x, abc, (f32x4*)out, out, n4, n);
}

// Round 6
// 226.943 us; speedup vs baseline: 1.0475x; 1.0475x over previous
//
#include <hip/hip_runtime.h>
#include <math.h>

#define N_LAYERS 101

// Clang-native vector type: __builtin_nontemporal_{load,store} require it.
typedef float f32x4 __attribute__((ext_vector_type(4)));

// Prepass (1 block, 128 threads): coalesced load of w/b, thread 0 composes
// the 101 layers into F(t) = max(A*t + B, C). Valid when w_i >= 0 for i>=1:
//   max(w*max(At+B,C)+b, 0) = max(wA*t + wB+b, max(wC+b, 0)).
// Also stages w/b copies into the workspace for the exact fallback path.
__global__ void collapse_abc(const float* __restrict__ w,
                             const float* __restrict__ b,
                             float* __restrict__ abc) {
    __shared__ float ws[N_LAYERS];
    __shared__ float bs[N_LAYERS];
    const int t = threadIdx.x;
    if (t < N_LAYERS) { ws[t] = w[t]; bs[t] = b[t]; }
    __syncthreads();
    if (t == 0) {
        float A = ws[0], B = bs[0], C = 0.0f, ok = 1.0f;
        for (int i = 1; i < N_LAYERS; ++i) {
            const float wi = ws[i], bi = bs[i];
            if (wi < 0.0f) ok = 0.0f;
            A = wi * A;
            B = fmaf(wi, B, bi);
            C = fmaxf(fmaf(wi, C, bi), 0.0f);
        }
        abc[0] = A; abc[1] = B; abc[2] = C; abc[3] = ok;
    }
    if (t < N_LAYERS) {
        abc[8 + t] = w[t];
        abc[8 + N_LAYERS + t] = b[t];
    }
}

// Main kernel. The harness poisons 640 MB (d_out + d_ws) through L2/L3
// right before every timed launch, so the cache is full of dirty garbage.
// Input is read-once, output is write-once: nontemporal on BOTH sides
// bypasses the poisoned hierarchy (no read-allocate evictions of dirty
// lines racing our traffic, no write-allocate). 8 independent dwordx4
// loads in flight per thread, fully unrolled (static reg indices).
__global__ __launch_bounds__(256) void apply_affine(
    const f32x4* __restrict__ x4,
    const float* __restrict__ x,        // scalar view for tail
    const float* __restrict__ abc,
    f32x4* __restrict__ o4,
    float* __restrict__ o,
    int n4, int n) {
    const float A = abc[0], B = abc[1], C = abc[2];
    const bool fast = (abc[3] != 0.0f);   // block-uniform branch

    const int gtid = blockIdx.x * blockDim.x + threadIdx.x;
    const int gsz  = gridDim.x * blockDim.x;

    if (fast) {
        // Block-chunked x8: block owns [b*2048, b*2048+2048) float4s;
        // thread t handles t + k*256, k=0..7. Coalesced 1KB/wave/instr.
        for (int base = blockIdx.x * (256 * 8) + threadIdx.x;
             base < n4; base += gsz * 8) {
            f32x4 v0, v1, v2, v3, v4, v5, v6, v7;
            const int i0 = base;
            const int i1 = base + 256,  i2 = base + 512,  i3 = base + 768;
            const int i4 = base + 1024, i5 = base + 1280, i6 = base + 1536;
            const int i7 = base + 1792;
            if (i0 < n4) v0 = __builtin_nontemporal_load(x4 + i0);
            if (i1 < n4) v1 = __builtin_nontemporal_load(x4 + i1);
            if (i2 < n4) v2 = __builtin_nontemporal_load(x4 + i2);
            if (i3 < n4) v3 = __builtin_nontemporal_load(x4 + i3);
            if (i4 < n4) v4 = __builtin_nontemporal_load(x4 + i4);
            if (i5 < n4) v5 = __builtin_nontemporal_load(x4 + i5);
            if (i6 < n4) v6 = __builtin_nontemporal_load(x4 + i6);
            if (i7 < n4) v7 = __builtin_nontemporal_load(x4 + i7);
            #define APPLY(v) \
                v.x = fmaxf(fmaf(A, v.x, B), C); \
                v.y = fmaxf(fmaf(A, v.y, B), C); \
                v.z = fmaxf(fmaf(A, v.z, B), C); \
                v.w = fmaxf(fmaf(A, v.w, B), C);
            if (i0 < n4) { APPLY(v0); __builtin_nontemporal_store(v0, o4 + i0); }
            if (i1 < n4) { APPLY(v1); __builtin_nontemporal_store(v1, o4 + i1); }
            if (i2 < n4) { APPLY(v2); __builtin_nontemporal_store(v2, o4 + i2); }
            if (i3 < n4) { APPLY(v3); __builtin_nontemporal_store(v3, o4 + i3); }
            if (i4 < n4) { APPLY(v4); __builtin_nontemporal_store(v4, o4 + i4); }
            if (i5 < n4) { APPLY(v5); __builtin_nontemporal_store(v5, o4 + i5); }
            if (i6 < n4) { APPLY(v6); __builtin_nontemporal_store(v6, o4 + i6); }
            if (i7 < n4) { APPLY(v7); __builtin_nontemporal_store(v7, o4 + i7); }
            #undef APPLY
        }
        // Scalar tail (n % 4) — empty for this problem (n = 2^25).
        for (int i = n4 * 4 + gtid; i < n; i += gsz) {
            o[i] = fmaxf(fmaf(A, x[i], B), C);
        }
    } else {
        // Exact fallback (never taken for these inputs): full 101-layer
        // chain, w/b staged by the prepass into the workspace. unroll 1
        // keeps the deep loop from inflating VGPR allocation.
        __shared__ float ws[N_LAYERS];
        __shared__ float bs[N_LAYERS];
        for (int i = threadIdx.x; i < N_LAYERS; i += blockDim.x) {
            ws[i] = abc[8 + i];
            bs[i] = abc[8 + N_LAYERS + i];
        }
        __syncthreads();
        #pragma unroll 1
        for (int i = gtid; i < n4; i += gsz) {
            f32x4 v = x4[i];
            #pragma unroll 1
            for (int l = 0; l < N_LAYERS; ++l) {
                const float wl = ws[l], bl = bs[l];
                v.x = fmaxf(fmaf(wl, v.x, bl), 0.0f);
                v.y = fmaxf(fmaf(wl, v.y, bl), 0.0f);
                v.z = fmaxf(fmaf(wl, v.z, bl), 0.0f);
                v.w = fmaxf(fmaf(wl, v.w, bl), 0.0f);
            }
            o4[i] = v;
        }
        #pragma unroll 1
        for (int i = n4 * 4 + gtid; i < n; i += gsz) {
            float v = x[i];
            #pragma unroll 1
            for (int l = 0; l < N_LAYERS; ++l) {
                v = fmaxf(fmaf(ws[l], v, bs[l]), 0.0f);
            }
            o[i] = v;
        }
    }
}

extern "C" void kernel_launch(void* const* d_in, const int* in_sizes, int n_in,
                              void* d_out, int out_size, void* d_ws, size_t ws_size,
                              hipStream_t stream) {
    const float* x = (const float*)d_in[0];
    const float* w = (const float*)d_in[1];
    const float* b = (const float*)d_in[2];
    float* out = (float*)d_out;
    float* abc = (float*)d_ws;            // [0..3]=A,B,C,ok  [8..]=w,b copies

    const int n  = in_sizes[0];
    const int n4 = n / 4;

    collapse_abc<<<1, 128, 0, stream>>>(w, b, abc);

    // 8 float4 per thread per pass; n4 = 2^23 -> exactly 4096 blocks.
    int blocks = (n4 + 2047) / 2048;
    if (blocks > 8192) blocks = 8192;
    apply_affine<<<blocks, 256, 0, stream>>>(
        (const f32x4*)x, x, abc, (f32x4*)out, out, n4, n);
}

// Round 8
// 223.255 us; speedup vs baseline: 1.0648x; 1.0165x over previous
//
#include <hip/hip_runtime.h>
#include <math.h>

#define N_LAYERS 101

// Clang-native vector type: __builtin_nontemporal_{load,store} require it.
typedef float f32x4 __attribute__((ext_vector_type(4)));

#define PER_THREAD 16                    // float4 per thread
#define BLOCK_SPAN (256 * PER_THREAD)    // 4096 float4 per block

// Single kernel, no prepass dispatch.
//
// Math: 101 x relu(h*w+b) collapses to F(t) = max(A*t + B, C) when w_i >= 0
// for i >= 1 (max(At+B,C) is closed under h -> max(w*h+b, 0), w >= 0):
//   max(w*max(At+B,C)+b, 0) = max(wA*t + wB+b, max(wC+b, 0)).
// The collapse runs per-wave from UNIFORM scalar loads (w/b pointers are
// uniform -> s_load, ~2 cache lines) and is placed AFTER the x-load issue so
// its ~800-cycle dependent chain hides under the ~900-cycle HBM latency.
//
// Memory: the harness poisons 640 MB (d_out+d_ws) through L2/L3 right before
// every timed launch. Input is read-once, output write-once: nontemporal on
// BOTH sides avoids read-allocate evictions of dirty poison lines and
// write-allocate churn. 16 independent dwordx4 loads in flight per thread;
// 2048 blocks x 4 waves = exactly 32 waves/CU (one resident generation).
__global__ __launch_bounds__(256) void apply_affine(
    const f32x4* __restrict__ x4,
    const float* __restrict__ x,        // scalar view for tail
    const float* __restrict__ w,
    const float* __restrict__ b,
    f32x4* __restrict__ o4,
    float* __restrict__ o,
    int n4, int n) {
    const int t    = threadIdx.x;
    const int base = blockIdx.x * BLOCK_SPAN + t;
    // Uniform per block: every one of this block's accesses is in range.
    const bool full = (int)((blockIdx.x + 1) * BLOCK_SPAN) <= n4;

    // --- Issue the streaming loads FIRST (fast path) ---
    f32x4 v0, v1, v2, v3, v4, v5, v6, v7, v8, v9, v10, v11, v12, v13, v14, v15;
    if (full) {
        v0  = __builtin_nontemporal_load(x4 + base + 0  * 256);
        v1  = __builtin_nontemporal_load(x4 + base + 1  * 256);
        v2  = __builtin_nontemporal_load(x4 + base + 2  * 256);
        v3  = __builtin_nontemporal_load(x4 + base + 3  * 256);
        v4  = __builtin_nontemporal_load(x4 + base + 4  * 256);
        v5  = __builtin_nontemporal_load(x4 + base + 5  * 256);
        v6  = __builtin_nontemporal_load(x4 + base + 6  * 256);
        v7  = __builtin_nontemporal_load(x4 + base + 7  * 256);
        v8  = __builtin_nontemporal_load(x4 + base + 8  * 256);
        v9  = __builtin_nontemporal_load(x4 + base + 9  * 256);
        v10 = __builtin_nontemporal_load(x4 + base + 10 * 256);
        v11 = __builtin_nontemporal_load(x4 + base + 11 * 256);
        v12 = __builtin_nontemporal_load(x4 + base + 12 * 256);
        v13 = __builtin_nontemporal_load(x4 + base + 13 * 256);
        v14 = __builtin_nontemporal_load(x4 + base + 14 * 256);
        v15 = __builtin_nontemporal_load(x4 + base + 15 * 256);
    }

    // --- Uniform collapse (hidden under the load latency above) ---
    float A = w[0], B = b[0], C = 0.0f;
    bool ok = true;
    for (int i = 1; i < N_LAYERS; ++i) {
        const float wi = w[i], bi = b[i];
        ok = ok && (wi >= 0.0f);
        A = wi * A;
        B = fmaf(wi, B, bi);
        C = fmaxf(fmaf(wi, C, bi), 0.0f);
    }

    if (ok) {
        #define APPLY(v) \
            v.x = fmaxf(fmaf(A, v.x, B), C); \
            v.y = fmaxf(fmaf(A, v.y, B), C); \
            v.z = fmaxf(fmaf(A, v.z, B), C); \
            v.w = fmaxf(fmaf(A, v.w, B), C);
        if (full) {
            APPLY(v0);  __builtin_nontemporal_store(v0,  o4 + base + 0  * 256);
            APPLY(v1);  __builtin_nontemporal_store(v1,  o4 + base + 1  * 256);
            APPLY(v2);  __builtin_nontemporal_store(v2,  o4 + base + 2  * 256);
            APPLY(v3);  __builtin_nontemporal_store(v3,  o4 + base + 3  * 256);
            APPLY(v4);  __builtin_nontemporal_store(v4,  o4 + base + 4  * 256);
            APPLY(v5);  __builtin_nontemporal_store(v5,  o4 + base + 5  * 256);
            APPLY(v6);  __builtin_nontemporal_store(v6,  o4 + base + 6  * 256);
            APPLY(v7);  __builtin_nontemporal_store(v7,  o4 + base + 7  * 256);
            APPLY(v8);  __builtin_nontemporal_store(v8,  o4 + base + 8  * 256);
            APPLY(v9);  __builtin_nontemporal_store(v9,  o4 + base + 9  * 256);
            APPLY(v10); __builtin_nontemporal_store(v10, o4 + base + 10 * 256);
            APPLY(v11); __builtin_nontemporal_store(v11, o4 + base + 11 * 256);
            APPLY(v12); __builtin_nontemporal_store(v12, o4 + base + 12 * 256);
            APPLY(v13); __builtin_nontemporal_store(v13, o4 + base + 13 * 256);
            APPLY(v14); __builtin_nontemporal_store(v14, o4 + base + 14 * 256);
            APPLY(v15); __builtin_nontemporal_store(v15, o4 + base + 15 * 256);
        } else {
            // Partial last block (never taken for n = 2^25): guarded loop.
            #pragma unroll 1
            for (int k = 0; k < PER_THREAD; ++k) {
                const int i = base + k * 256;
                if (i < n4) {
                    f32x4 v = __builtin_nontemporal_load(x4 + i);
                    APPLY(v);
                    __builtin_nontemporal_store(v, o4 + i);
                }
            }
            // Scalar tail (n % 4 != 0) — empty for this problem.
            for (int i = n4 * 4 + t; i < n; i += 256) {
                o[i] = fmaxf(fmaf(A, x[i], B), C);
            }
        }
        #undef APPLY
    } else {
        // Exact fallback (never taken for these inputs): full 101-layer
        // chain, w/b staged in LDS. unroll 1 keeps the deep loop from
        // inflating the whole kernel's VGPR allocation.
        __shared__ float ws[N_LAYERS];
        __shared__ float bs[N_LAYERS];
        for (int i = t; i < N_LAYERS; i += blockDim.x) {
            ws[i] = w[i];
            bs[i] = b[i];
        }
        __syncthreads();
        const int gtid = blockIdx.x * blockDim.x + t;
        const int gsz  = gridDim.x * blockDim.x;
        #pragma unroll 1
        for (int i = gtid; i < n4; i += gsz) {
            f32x4 v = x4[i];
            #pragma unroll 1
            for (int l = 0; l < N_LAYERS; ++l) {
                const float wl = ws[l], bl = bs[l];
                v.x = fmaxf(fmaf(wl, v.x, bl), 0.0f);
                v.y = fmaxf(fmaf(wl, v.y, bl), 0.0f);
                v.z = fmaxf(fmaf(wl, v.z, bl), 0.0f);
                v.w = fmaxf(fmaf(wl, v.w, bl), 0.0f);
            }
            o4[i] = v;
        }
        #pragma unroll 1
        for (int i = n4 * 4 + gtid; i < n; i += gsz) {
            float v = x[i];
            #pragma unroll 1
            for (int l = 0; l < N_LAYERS; ++l) {
                v = fmaxf(fmaf(ws[l], v, bs[l]), 0.0f);
            }
            o[i] = v;
        }
    }
}

extern "C" void kernel_launch(void* const* d_in, const int* in_sizes, int n_in,
                              void* d_out, int out_size, void* d_ws, size_t ws_size,
                              hipStream_t stream) {
    const float* x = (const float*)d_in[0];
    const float* w = (const float*)d_in[1];
    const float* b = (const float*)d_in[2];
    float* out = (float*)d_out;

    const int n  = in_sizes[0];
    const int n4 = n / 4;

    // n4 = 2^23 -> exactly 2048 full blocks (32 waves/CU, one generation).
    int blocks = (n4 + BLOCK_SPAN - 1) / BLOCK_SPAN;
    if (blocks < 1) blocks = 1;
    apply_affine<<<blocks, 256, 0, stream>>>(
        (const f32x4*)x, x, w, b, (f32x4*)out, out, n4, n);
}